// Round 2
// baseline (8440.290 us; speedup 1.0000x reference)
//
#include <hip/hip_runtime.h>

#define DD 128
#define KTOT 384
#define ROWS_PER_BLOCK 32

// ---------------- edge dtype probe: int64 arrays have all-zero odd int32 words ----------
__global__ __launch_bounds__(256) void detect_i32(const int* __restrict__ p, int nodd,
                                                  int* __restrict__ flag)
{
    int i = blockIdx.x * 256 + threadIdx.x;
    if (i < nodd && p[2 * i + 1] != 0) atomicOr(flag, 1);
}

__global__ __launch_bounds__(256) void convert_edges(const void* __restrict__ src, int n,
                                                     const int* __restrict__ flag,
                                                     int* __restrict__ dst)
{
    int i = blockIdx.x * 256 + threadIdx.x;
    if (i >= n) return;
    if (*flag) {
        dst[i] = ((const int*)src)[i];
    } else {
        dst[i] = (int)((const long long*)src)[i];
    }
}

// ---------------- weight prep: Wc[l][dst][k][i] = combined, transposed ----------------
__global__ __launch_bounds__(256) void build_wcomb(
    const float* __restrict__ Wl, const float* __restrict__ bl,
    const float* __restrict__ Wr, float* __restrict__ Wc, float* __restrict__ bc)
{
    int idx = blockIdx.x * 256 + threadIdx.x;
    if (idx < 2 * 2 * KTOT * DD) {
        int i  = idx & 127;
        int t1 = idx >> 7;
        int k  = t1 % KTOT;
        int t2 = t1 / KTOT;
        int dt = t2 & 1;      // 0 = dst d, 1 = dst m
        int l  = t2 >> 1;
        int ta = dt ? 1 : 0;  // d: dd(0), m: mm(1)
        int tb = dt ? 2 : 3;  // d: md(3), m: dm(2)
        float v;
        if (k < 128) {
            v = Wl[(((size_t)(l * 4 + ta) * 128 + i) << 7) + k];
        } else if (k < 256) {
            v = Wl[(((size_t)(l * 4 + tb) * 128 + i) << 7) + (k - 128)];
        } else {
            int kk = k - 256;
            v = Wr[(((size_t)(l * 4 + ta) * 128 + i) << 7) + kk]
              + Wr[(((size_t)(l * 4 + tb) * 128 + i) << 7) + kk];
        }
        Wc[idx] = v;
    }
    if (idx < 512) {
        int i  = idx & 127;
        int t2 = idx >> 7;
        int dt = t2 & 1;
        int l  = t2 >> 1;
        int ta = dt ? 1 : 0;
        int tb = dt ? 2 : 3;
        bc[idx] = bl[(l * 4 + ta) * 128 + i] + bl[(l * 4 + tb) * 128 + i];
    }
}

// ---------------- degree counts (float, layer-invariant) ----------------
__global__ __launch_bounds__(256) void count_edges(const int* __restrict__ ei, int E,
                                                   float* __restrict__ cnt)
{
    int e = blockIdx.x * 256 + threadIdx.x;
    if (e < E) atomicAdd(&cnt[ei[E + e]], 1.0f);
}

__global__ __launch_bounds__(256) void make_inv(float* __restrict__ buf, int n)
{
    int i = blockIdx.x * 256 + threadIdx.x;
    if (i < n) buf[i] = 1.0f / fmaxf(buf[i], 1.0f);
}

// ---------------- scatter-add: agg[dst] += x[src], 32 lanes/edge, float4 ----------------
__global__ __launch_bounds__(256) void scatter_add(
    const float* __restrict__ x, const int* __restrict__ ei, int E,
    float* __restrict__ agg)
{
    long long t = (long long)blockIdx.x * 256 + threadIdx.x;
    int e = (int)(t >> 5);
    if (e >= E) return;
    int q = (int)(t & 31);
    int s = ei[e];
    int d = ei[E + e];
    float4 v = *(const float4*)(x + (size_t)s * DD + q * 4);
    float* p = agg + (size_t)d * DD + q * 4;
    atomicAdd(p + 0, v.x);
    atomicAdd(p + 1, v.y);
    atomicAdd(p + 2, v.z);
    atomicAdd(p + 3, v.w);
}

// ---------------- fused GEMM: out = [agg_a*inv_a | agg_b*inv_b | x] @ Wc + bc (+relu) ----
__global__ __launch_bounds__(256) void gemm_fused(
    const float* __restrict__ agg_a, const float* __restrict__ inv_a,
    const float* __restrict__ agg_b, const float* __restrict__ inv_b,
    const float* __restrict__ xs, const float* __restrict__ W,
    const float* __restrict__ bias, float* __restrict__ out, int relu)
{
    __shared__ float As[ROWS_PER_BLOCK][KTOT];   // 48 KiB
    const int tid  = threadIdx.x;
    const int row0 = blockIdx.x * ROWS_PER_BLOCK;

    // stage 32 rows x 384 cols (mean-scale fused): 3072 float4 / 256 thr = 12 each
    #pragma unroll
    for (int it = 0; it < 12; ++it) {
        int i   = tid + it * 256;
        int row = i / 96;
        int rem = i - row * 96;
        int seg = rem >> 5;
        int q   = rem & 31;
        int r   = row0 + row;
        const float* src;
        float sc;
        if (seg == 0)      { src = agg_a; sc = inv_a[r]; }
        else if (seg == 1) { src = agg_b; sc = inv_b[r]; }
        else               { src = xs;    sc = 1.0f; }
        float4 v = *(const float4*)(src + (size_t)r * DD + q * 4);
        float* dstp = &As[row][seg * 128 + q * 4];
        dstp[0] = v.x * sc; dstp[1] = v.y * sc; dstp[2] = v.z * sc; dstp[3] = v.w * sc;
    }
    __syncthreads();

    const int wave = tid >> 6;
    const int lane = tid & 63;
    const int c0   = lane << 1;          // 2 columns per lane
    const int r0   = wave * 8;           // 8 rows per wave

    float2 acc[8];
    #pragma unroll
    for (int r = 0; r < 8; ++r) acc[r] = make_float2(0.f, 0.f);

    for (int k = 0; k < KTOT; k += 4) {
        float4 a[8];
        #pragma unroll
        for (int r = 0; r < 8; ++r) a[r] = *(const float4*)&As[r0 + r][k];
        #pragma unroll
        for (int kk = 0; kk < 4; ++kk) {
            float2 w2 = *(const float2*)(W + (size_t)(k + kk) * DD + c0);
            #pragma unroll
            for (int r = 0; r < 8; ++r) {
                float av = (kk == 0) ? a[r].x : (kk == 1) ? a[r].y : (kk == 2) ? a[r].z : a[r].w;
                acc[r].x = fmaf(av, w2.x, acc[r].x);
                acc[r].y = fmaf(av, w2.y, acc[r].y);
            }
        }
    }

    float2 bb = *(const float2*)(bias + c0);
    #pragma unroll
    for (int r = 0; r < 8; ++r) {
        float ox = acc[r].x + bb.x;
        float oy = acc[r].y + bb.y;
        if (relu) { ox = fmaxf(ox, 0.f); oy = fmaxf(oy, 0.f); }
        *(float2*)(out + (size_t)(row0 + r0 + r) * DD + c0) = make_float2(ox, oy);
    }
}

extern "C" void kernel_launch(void* const* d_in, const int* in_sizes, int n_in,
                              void* d_out, int out_size, void* d_ws, size_t ws_size,
                              hipStream_t stream)
{
    const float* x_d = (const float*)d_in[0];
    const float* x_m = (const float*)d_in[1];
    const float* Wl  = (const float*)d_in[6];
    const float* bl  = (const float*)d_in[7];
    const float* Wr  = (const float*)d_in[8];
    float* out = (float*)d_out;

    const int N    = in_sizes[0] / DD;
    const int E_dd = in_sizes[2] / 2;
    const int E_mm = in_sizes[3] / 2;
    const int E_dm = in_sizes[4] / 2;
    const int E_md = in_sizes[5] / 2;

    char* ws = (char*)d_ws;
    size_t off = 0;
    auto alloc = [&](size_t bytes) {
        void* p = ws + off;
        off += (bytes + 255) & ~(size_t)255;
        return p;
    };
    float* agg0   = (float*)alloc((size_t)N * DD * 4);
    float* agg1   = (float*)alloc((size_t)N * DD * 4);   // contiguous with agg0 (N*DD*4 % 256 == 0)
    float* xb_d   = (float*)alloc((size_t)N * DD * 4);
    float* xb_m   = (float*)alloc((size_t)N * DD * 4);
    float* inv_all= (float*)alloc((size_t)4 * N * 4);    // one contiguous block: dd|md|mm|dm
    float* Wc     = (float*)alloc((size_t)2 * 2 * KTOT * DD * 4);
    float* bc     = (float*)alloc((size_t)512 * 4);
    int*   ce_dd  = (int*)alloc((size_t)2 * E_dd * 4);
    int*   ce_mm  = (int*)alloc((size_t)2 * E_mm * 4);
    int*   ce_dm  = (int*)alloc((size_t)2 * E_dm * 4);
    int*   ce_md  = (int*)alloc((size_t)2 * E_md * 4);
    int*   flag   = (int*)alloc(256);

    float* inv_dd = inv_all;
    float* inv_md = inv_all + N;
    float* inv_mm = inv_all + 2 * N;
    float* inv_dm = inv_all + 3 * N;

    // ---- edge dtype normalize: probe int32-vs-int64, convert to int32 in ws ----
    hipMemsetAsync(flag, 0, 256, stream);
    detect_i32<<<(1024 + 255) / 256, 256, 0, stream>>>((const int*)d_in[2], 1024, flag);
    convert_edges<<<(2 * E_dd + 255) / 256, 256, 0, stream>>>(d_in[2], 2 * E_dd, flag, ce_dd);
    convert_edges<<<(2 * E_mm + 255) / 256, 256, 0, stream>>>(d_in[3], 2 * E_mm, flag, ce_mm);
    convert_edges<<<(2 * E_dm + 255) / 256, 256, 0, stream>>>(d_in[4], 2 * E_dm, flag, ce_dm);
    convert_edges<<<(2 * E_md + 255) / 256, 256, 0, stream>>>(d_in[5], 2 * E_md, flag, ce_md);

    // ---- prep: degree counts (once; layer-invariant) + combined weights ----
    hipMemsetAsync(inv_all, 0, (size_t)4 * N * 4, stream);
    count_edges<<<(E_dd + 255) / 256, 256, 0, stream>>>(ce_dd, E_dd, inv_dd);
    count_edges<<<(E_md + 255) / 256, 256, 0, stream>>>(ce_md, E_md, inv_md);
    count_edges<<<(E_mm + 255) / 256, 256, 0, stream>>>(ce_mm, E_mm, inv_mm);
    count_edges<<<(E_dm + 255) / 256, 256, 0, stream>>>(ce_dm, E_dm, inv_dm);
    make_inv<<<(4 * N + 255) / 256, 256, 0, stream>>>(inv_all, 4 * N);
    build_wcomb<<<(2 * 2 * KTOT * DD + 255) / 256, 256, 0, stream>>>(Wl, bl, Wr, Wc, bc);

    const float* xd_cur = x_d;
    const float* xm_cur = x_m;
    for (int l = 0; l < 2; ++l) {
        float* od = (l == 1) ? out : xb_d;
        float* om = (l == 1) ? out + (size_t)N * DD : xb_m;
        int relu = (l == 0);

        // ---- dst type d: agg_dd (from x_d via e_dd) + agg_md (from x_m via e_md) ----
        hipMemsetAsync(agg0, 0, (size_t)2 * N * DD * 4, stream);
        scatter_add<<<(int)(((size_t)E_dd * 32 + 255) / 256), 256, 0, stream>>>(xd_cur, ce_dd, E_dd, agg0);
        scatter_add<<<(int)(((size_t)E_md * 32 + 255) / 256), 256, 0, stream>>>(xm_cur, ce_md, E_md, agg1);
        gemm_fused<<<N / ROWS_PER_BLOCK, 256, 0, stream>>>(
            agg0, inv_dd, agg1, inv_md, xd_cur,
            Wc + (size_t)(l * 2 + 0) * KTOT * DD, bc + (l * 2 + 0) * DD, od, relu);

        // ---- dst type m: agg_mm (from x_m via e_mm) + agg_dm (from x_d via e_dm) ----
        hipMemsetAsync(agg0, 0, (size_t)2 * N * DD * 4, stream);
        scatter_add<<<(int)(((size_t)E_mm * 32 + 255) / 256), 256, 0, stream>>>(xm_cur, ce_mm, E_mm, agg0);
        scatter_add<<<(int)(((size_t)E_dm * 32 + 255) / 256), 256, 0, stream>>>(xd_cur, ce_dm, E_dm, agg1);
        gemm_fused<<<N / ROWS_PER_BLOCK, 256, 0, stream>>>(
            agg0, inv_mm, agg1, inv_dm, xm_cur,
            Wc + (size_t)(l * 2 + 1) * KTOT * DD, bc + (l * 2 + 1) * DD, om, relu);

        xd_cur = od;
        xm_cur = om;
    }
}

// Round 3
// 1475.097 us; speedup vs baseline: 5.7219x; 5.7219x over previous
//
#include <hip/hip_runtime.h>

#define DD 128
#define KTOT 384
#define ROWS_PER_BLOCK 32
#define SCAN_TILE 1024

// ---------------- edge dtype probe: int64 arrays have all-zero odd int32 words ----------
__global__ __launch_bounds__(256) void detect_i32(const int* __restrict__ p, int nodd,
                                                  int* __restrict__ flag)
{
    int i = blockIdx.x * 256 + threadIdx.x;
    if (i < nodd && p[2 * i + 1] != 0) atomicOr(flag, 1);
}

__global__ __launch_bounds__(256) void convert_edges(const void* __restrict__ src, int n,
                                                     const int* __restrict__ flag,
                                                     int* __restrict__ dst)
{
    int i = blockIdx.x * 256 + threadIdx.x;
    if (i >= n) return;
    if (*flag) dst[i] = ((const int*)src)[i];
    else       dst[i] = (int)((const long long*)src)[i];
}

// ---------------- weight prep: Wc[l][dst][k][i] = combined, transposed ----------------
__global__ __launch_bounds__(256) void build_wcomb(
    const float* __restrict__ Wl, const float* __restrict__ bl,
    const float* __restrict__ Wr, float* __restrict__ Wc, float* __restrict__ bc)
{
    int idx = blockIdx.x * 256 + threadIdx.x;
    if (idx < 2 * 2 * KTOT * DD) {
        int i  = idx & 127;
        int t1 = idx >> 7;
        int k  = t1 % KTOT;
        int t2 = t1 / KTOT;
        int dt = t2 & 1;      // 0 = dst d, 1 = dst m
        int l  = t2 >> 1;
        int ta = dt ? 1 : 0;  // d: dd(0), m: mm(1)
        int tb = dt ? 2 : 3;  // d: md(3), m: dm(2)
        float v;
        if (k < 128) {
            v = Wl[(((size_t)(l * 4 + ta) * 128 + i) << 7) + k];
        } else if (k < 256) {
            v = Wl[(((size_t)(l * 4 + tb) * 128 + i) << 7) + (k - 128)];
        } else {
            int kk = k - 256;
            v = Wr[(((size_t)(l * 4 + ta) * 128 + i) << 7) + kk]
              + Wr[(((size_t)(l * 4 + tb) * 128 + i) << 7) + kk];
        }
        Wc[idx] = v;
    }
    if (idx < 512) {
        int i  = idx & 127;
        int t2 = idx >> 7;
        int dt = t2 & 1;
        int l  = t2 >> 1;
        int ta = dt ? 1 : 0;
        int tb = dt ? 2 : 3;
        bc[idx] = bl[(l * 4 + ta) * 128 + i] + bl[(l * 4 + tb) * 128 + i];
    }
}

// ---------------- degree counts (int, layer-invariant) ----------------
__global__ __launch_bounds__(256) void count_edges_i(const int* __restrict__ ei, int E,
                                                     int* __restrict__ cnt)
{
    int e = blockIdx.x * 256 + threadIdx.x;
    if (e < E) atomicAdd(&cnt[ei[E + e]], 1);
}

__global__ __launch_bounds__(256) void make_inv(const int* __restrict__ cnt,
                                                float* __restrict__ inv, int n)
{
    int i = blockIdx.x * 256 + threadIdx.x;
    if (i < n) inv[i] = 1.0f / (float)max(cnt[i], 1);
}

// ---------------- exclusive scan (3-pass) ----------------
__global__ __launch_bounds__(256) void scan1(const int* __restrict__ in, int n,
                                             int* __restrict__ out, int* __restrict__ bsum)
{
    __shared__ int s[256];
    const int t = threadIdx.x;
    const int base = blockIdx.x * SCAN_TILE + t * 4;
    int c0 = (base + 0) < n ? in[base + 0] : 0;
    int c1 = (base + 1) < n ? in[base + 1] : 0;
    int c2 = (base + 2) < n ? in[base + 2] : 0;
    int c3 = (base + 3) < n ? in[base + 3] : 0;
    int tsum = c0 + c1 + c2 + c3;
    s[t] = tsum;
    __syncthreads();
    for (int d = 1; d < 256; d <<= 1) {
        int v = (t >= d) ? s[t - d] : 0;
        __syncthreads();
        s[t] += v;
        __syncthreads();
    }
    int excl = s[t] - tsum;
    if (base + 0 < n) out[base + 0] = excl;
    if (base + 1 < n) out[base + 1] = excl + c0;
    if (base + 2 < n) out[base + 2] = excl + c0 + c1;
    if (base + 3 < n) out[base + 3] = excl + c0 + c1 + c2;
    if (t == 255) bsum[blockIdx.x] = s[255];
}

__global__ __launch_bounds__(1024) void scan_bsum(int* __restrict__ bsum, int nb)
{
    __shared__ int s[1024];
    const int t = threadIdx.x;
    int v = (t < nb) ? bsum[t] : 0;
    s[t] = v;
    __syncthreads();
    for (int d = 1; d < 1024; d <<= 1) {
        int u = (t >= d) ? s[t - d] : 0;
        __syncthreads();
        s[t] += u;
        __syncthreads();
    }
    if (t < nb) bsum[t] = s[t] - v;   // exclusive
}

__global__ __launch_bounds__(256) void scan_add(int* __restrict__ rp, int* __restrict__ cur,
                                                int n, const int* __restrict__ bsum)
{
    int i = blockIdx.x * 256 + threadIdx.x;
    if (i < n) {
        int v = rp[i] + bsum[i / SCAN_TILE];
        rp[i] = v;
        cur[i] = v;
    }
}

// ---------------- CSR fill: col[slot] = src, slot via per-dst cursor ----------------
__global__ __launch_bounds__(256) void fill_csr(const int* __restrict__ ei, int E,
                                                int* __restrict__ cur, int* __restrict__ col)
{
    int e = blockIdx.x * 256 + threadIdx.x;
    if (e < E) {
        int d = ei[E + e];
        int slot = atomicAdd(&cur[d], 1);
        col[slot] = ei[e];
    }
}

// ---------------- gather-aggregate both edge types of one dst type ----------------
__global__ __launch_bounds__(256) void aggregate2(
    const float* __restrict__ xa, const int* __restrict__ rpa, const int* __restrict__ cnta,
    const int* __restrict__ cola, const float* __restrict__ inva,
    const float* __restrict__ xb, const int* __restrict__ rpb, const int* __restrict__ cntb,
    const int* __restrict__ colb, const float* __restrict__ invb,
    float* __restrict__ agg0, float* __restrict__ agg1, int N)
{
    long long g = (long long)blockIdx.x * 256 + threadIdx.x;
    int node = (int)(g >> 5);
    int q    = (int)(g & 31);
    if (node >= N) return;

    float4 acc = make_float4(0.f, 0.f, 0.f, 0.f);
    int s0 = rpa[node], e0 = s0 + cnta[node];
    for (int j = s0; j < e0; ++j) {
        float4 v = *(const float4*)(xa + (size_t)cola[j] * DD + q * 4);
        acc.x += v.x; acc.y += v.y; acc.z += v.z; acc.w += v.w;
    }
    float sc = inva[node];
    acc.x *= sc; acc.y *= sc; acc.z *= sc; acc.w *= sc;
    *(float4*)(agg0 + (size_t)node * DD + q * 4) = acc;

    acc = make_float4(0.f, 0.f, 0.f, 0.f);
    int s1 = rpb[node], e1 = s1 + cntb[node];
    for (int j = s1; j < e1; ++j) {
        float4 v = *(const float4*)(xb + (size_t)colb[j] * DD + q * 4);
        acc.x += v.x; acc.y += v.y; acc.z += v.z; acc.w += v.w;
    }
    sc = invb[node];
    acc.x *= sc; acc.y *= sc; acc.z *= sc; acc.w *= sc;
    *(float4*)(agg1 + (size_t)node * DD + q * 4) = acc;
}

// ---------------- fused GEMM: out = [agg_a | agg_b | x] @ Wc + bc (+relu) ----------------
__global__ __launch_bounds__(256) void gemm_fused(
    const float* __restrict__ agg_a, const float* __restrict__ agg_b,
    const float* __restrict__ xs, const float* __restrict__ W,
    const float* __restrict__ bias, float* __restrict__ out, int relu)
{
    __shared__ float As[ROWS_PER_BLOCK][KTOT];   // 48 KiB
    const int tid  = threadIdx.x;
    const int row0 = blockIdx.x * ROWS_PER_BLOCK;

    #pragma unroll
    for (int it = 0; it < 12; ++it) {
        int i   = tid + it * 256;
        int row = i / 96;
        int rem = i - row * 96;
        int seg = rem >> 5;
        int q   = rem & 31;
        int r   = row0 + row;
        const float* src = (seg == 0) ? agg_a : (seg == 1) ? agg_b : xs;
        float4 v = *(const float4*)(src + (size_t)r * DD + q * 4);
        *(float4*)&As[row][seg * 128 + q * 4] = v;
    }
    __syncthreads();

    const int wave = tid >> 6;
    const int lane = tid & 63;
    const int c0   = lane << 1;          // 2 columns per lane
    const int r0   = wave * 8;           // 8 rows per wave

    float2 acc[8];
    #pragma unroll
    for (int r = 0; r < 8; ++r) acc[r] = make_float2(0.f, 0.f);

    for (int k = 0; k < KTOT; k += 4) {
        float4 a[8];
        #pragma unroll
        for (int r = 0; r < 8; ++r) a[r] = *(const float4*)&As[r0 + r][k];
        #pragma unroll
        for (int kk = 0; kk < 4; ++kk) {
            float2 w2 = *(const float2*)(W + (size_t)(k + kk) * DD + c0);
            #pragma unroll
            for (int r = 0; r < 8; ++r) {
                float av = (kk == 0) ? a[r].x : (kk == 1) ? a[r].y : (kk == 2) ? a[r].z : a[r].w;
                acc[r].x = fmaf(av, w2.x, acc[r].x);
                acc[r].y = fmaf(av, w2.y, acc[r].y);
            }
        }
    }

    float2 bb = *(const float2*)(bias + c0);
    #pragma unroll
    for (int r = 0; r < 8; ++r) {
        float ox = acc[r].x + bb.x;
        float oy = acc[r].y + bb.y;
        if (relu) { ox = fmaxf(ox, 0.f); oy = fmaxf(oy, 0.f); }
        *(float2*)(out + (size_t)(row0 + r0 + r) * DD + c0) = make_float2(ox, oy);
    }
}

extern "C" void kernel_launch(void* const* d_in, const int* in_sizes, int n_in,
                              void* d_out, int out_size, void* d_ws, size_t ws_size,
                              hipStream_t stream)
{
    const float* x_d = (const float*)d_in[0];
    const float* x_m = (const float*)d_in[1];
    const float* Wl  = (const float*)d_in[6];
    const float* bl  = (const float*)d_in[7];
    const float* Wr  = (const float*)d_in[8];
    float* out = (float*)d_out;

    const int N    = in_sizes[0] / DD;
    const int E_dd = in_sizes[2] / 2;
    const int E_mm = in_sizes[3] / 2;
    const int E_dm = in_sizes[4] / 2;
    const int E_md = in_sizes[5] / 2;

    char* ws = (char*)d_ws;
    size_t off = 0;
    auto alloc = [&](size_t bytes) {
        void* p = ws + off;
        off += (bytes + 255) & ~(size_t)255;
        return p;
    };
    float* agg0    = (float*)alloc((size_t)N * DD * 4);
    float* agg1    = (float*)alloc((size_t)N * DD * 4);
    float* xb_d    = (float*)alloc((size_t)N * DD * 4);
    float* xb_m    = (float*)alloc((size_t)N * DD * 4);
    int*   cnt_all = (int*)  alloc((size_t)4 * N * 4);   // dd|md|mm|dm
    float* inv_all = (float*)alloc((size_t)4 * N * 4);
    int*   rp_all  = (int*)  alloc((size_t)4 * N * 4);
    int*   cur_all = (int*)  alloc((size_t)4 * N * 4);
    int*   bsum    = (int*)  alloc((size_t)4 * 1024 * 4);
    float* Wc      = (float*)alloc((size_t)2 * 2 * KTOT * DD * 4);
    float* bc      = (float*)alloc((size_t)512 * 4);
    int*   ce_dd   = (int*)alloc((size_t)2 * E_dd * 4);
    int*   ce_mm   = (int*)alloc((size_t)2 * E_mm * 4);
    int*   ce_dm   = (int*)alloc((size_t)2 * E_dm * 4);
    int*   ce_md   = (int*)alloc((size_t)2 * E_md * 4);
    int*   col_dd  = (int*)alloc((size_t)E_dd * 4);
    int*   col_md  = (int*)alloc((size_t)E_md * 4);
    int*   col_mm  = (int*)alloc((size_t)E_mm * 4);
    int*   col_dm  = (int*)alloc((size_t)E_dm * 4);
    int*   flag    = (int*)alloc(256);

    // per-type views, order dd|md|mm|dm
    int*   cnt_dd = cnt_all,         *cnt_md = cnt_all + N, *cnt_mm = cnt_all + 2*N, *cnt_dm = cnt_all + 3*N;
    float* inv_dd = inv_all,         *inv_md = inv_all + N, *inv_mm = inv_all + 2*N, *inv_dm = inv_all + 3*N;
    int*   rp_dd  = rp_all,          *rp_md  = rp_all + N,  *rp_mm  = rp_all + 2*N,  *rp_dm  = rp_all + 3*N;
    int*   cur_dd = cur_all,         *cur_md = cur_all + N, *cur_mm = cur_all + 2*N, *cur_dm = cur_all + 3*N;

    // ---- edge dtype normalize ----
    hipMemsetAsync(flag, 0, 256, stream);
    detect_i32<<<4, 256, 0, stream>>>((const int*)d_in[2], 1024, flag);
    convert_edges<<<(2 * E_dd + 255) / 256, 256, 0, stream>>>(d_in[2], 2 * E_dd, flag, ce_dd);
    convert_edges<<<(2 * E_mm + 255) / 256, 256, 0, stream>>>(d_in[3], 2 * E_mm, flag, ce_mm);
    convert_edges<<<(2 * E_dm + 255) / 256, 256, 0, stream>>>(d_in[4], 2 * E_dm, flag, ce_dm);
    convert_edges<<<(2 * E_md + 255) / 256, 256, 0, stream>>>(d_in[5], 2 * E_md, flag, ce_md);

    // ---- degrees + inverse means ----
    hipMemsetAsync(cnt_all, 0, (size_t)4 * N * 4, stream);
    count_edges_i<<<(E_dd + 255) / 256, 256, 0, stream>>>(ce_dd, E_dd, cnt_dd);
    count_edges_i<<<(E_md + 255) / 256, 256, 0, stream>>>(ce_md, E_md, cnt_md);
    count_edges_i<<<(E_mm + 255) / 256, 256, 0, stream>>>(ce_mm, E_mm, cnt_mm);
    count_edges_i<<<(E_dm + 255) / 256, 256, 0, stream>>>(ce_dm, E_dm, cnt_dm);
    make_inv<<<(4 * N + 255) / 256, 256, 0, stream>>>(cnt_all, inv_all, 4 * N);

    // ---- CSR build (once; layer-invariant) ----
    const int nsb = (N + SCAN_TILE - 1) / SCAN_TILE;
    for (int t = 0; t < 4; ++t) {
        int* cnt = cnt_all + t * N;
        int* rp  = rp_all  + t * N;
        int* cur = cur_all + t * N;
        int* bs  = bsum + t * 1024;
        scan1<<<nsb, 256, 0, stream>>>(cnt, N, rp, bs);
        scan_bsum<<<1, 1024, 0, stream>>>(bs, nsb);
        scan_add<<<(N + 255) / 256, 256, 0, stream>>>(rp, cur, N, bs);
    }
    fill_csr<<<(E_dd + 255) / 256, 256, 0, stream>>>(ce_dd, E_dd, cur_dd, col_dd);
    fill_csr<<<(E_md + 255) / 256, 256, 0, stream>>>(ce_md, E_md, cur_md, col_md);
    fill_csr<<<(E_mm + 255) / 256, 256, 0, stream>>>(ce_mm, E_mm, cur_mm, col_mm);
    fill_csr<<<(E_dm + 255) / 256, 256, 0, stream>>>(ce_dm, E_dm, cur_dm, col_dm);

    build_wcomb<<<(2 * 2 * KTOT * DD + 255) / 256, 256, 0, stream>>>(Wl, bl, Wr, Wc, bc);

    const int agg_grid = (int)(((size_t)N * 32 + 255) / 256);
    const float* xd_cur = x_d;
    const float* xm_cur = x_m;
    for (int l = 0; l < 2; ++l) {
        float* od = (l == 1) ? out : xb_d;
        float* om = (l == 1) ? out + (size_t)N * DD : xb_m;
        int relu = (l == 0);

        // dst type d: agg_dd (x_d via e_dd) + agg_md (x_m via e_md)
        aggregate2<<<agg_grid, 256, 0, stream>>>(
            xd_cur, rp_dd, cnt_dd, col_dd, inv_dd,
            xm_cur, rp_md, cnt_md, col_md, inv_md, agg0, agg1, N);
        gemm_fused<<<N / ROWS_PER_BLOCK, 256, 0, stream>>>(
            agg0, agg1, xd_cur,
            Wc + (size_t)(l * 2 + 0) * KTOT * DD, bc + (l * 2 + 0) * DD, od, relu);

        // dst type m: agg_mm (x_m via e_mm) + agg_dm (x_d via e_dm)
        aggregate2<<<agg_grid, 256, 0, stream>>>(
            xm_cur, rp_mm, cnt_mm, col_mm, inv_mm,
            xd_cur, rp_dm, cnt_dm, col_dm, inv_dm, agg0, agg1, N);
        gemm_fused<<<N / ROWS_PER_BLOCK, 256, 0, stream>>>(
            agg0, agg1, xm_cur,
            Wc + (size_t)(l * 2 + 1) * KTOT * DD, bc + (l * 2 + 1) * DD, om, relu);

        xd_cur = od;
        xm_cur = om;
    }
}

// Round 4
// 835.436 us; speedup vs baseline: 10.1029x; 1.7657x over previous
//
#include <hip/hip_runtime.h>

#define DD 128
#define KTOT 384
#define BM 64
#define LDK 392          // 384 + 8 bf16 pad -> row stride 196 dwords (bank-uniform)
#define SCAN_TILE 1024

typedef __attribute__((ext_vector_type(8))) short short8;
typedef __attribute__((ext_vector_type(8))) unsigned short ushort8;
typedef __attribute__((ext_vector_type(4))) float floatx4;

__device__ __forceinline__ unsigned short f2b(float f) {
    union { float f; unsigned u; } v; v.f = f;
    return (unsigned short)((v.u + 0x7fffu + ((v.u >> 16) & 1u)) >> 16);
}
__device__ __forceinline__ float b2f(unsigned short u) {
    union { unsigned u; float f; } v; v.u = ((unsigned)u) << 16;
    return v.f;
}

// ---------------- edge dtype probe ----------------
__global__ __launch_bounds__(256) void detect_i32(const int* __restrict__ p, int nodd,
                                                  int* __restrict__ flag)
{
    int i = blockIdx.x * 256 + threadIdx.x;
    if (i < nodd && p[2 * i + 1] != 0) atomicOr(flag, 1);
}

__global__ __launch_bounds__(256) void convert_edges(const void* __restrict__ src, int n,
                                                     const int* __restrict__ flag,
                                                     int* __restrict__ dst)
{
    int i = blockIdx.x * 256 + threadIdx.x;
    if (i >= n) return;
    if (*flag) dst[i] = ((const int*)src)[i];
    else       dst[i] = (int)((const long long*)src)[i];
}

// ---------------- x -> bf16 ----------------
__global__ __launch_bounds__(256) void cvt_bf16(const float* __restrict__ in,
                                                unsigned short* __restrict__ out, int n8)
{
    int i = blockIdx.x * 256 + threadIdx.x;
    if (i >= n8) return;
    float4 v0 = *(const float4*)(in + (size_t)i * 8);
    float4 v1 = *(const float4*)(in + (size_t)i * 8 + 4);
    ushort8 r;
    r[0]=f2b(v0.x); r[1]=f2b(v0.y); r[2]=f2b(v0.z); r[3]=f2b(v0.w);
    r[4]=f2b(v1.x); r[5]=f2b(v1.y); r[6]=f2b(v1.z); r[7]=f2b(v1.w);
    *(ushort8*)(out + (size_t)i * 8) = r;
}

// ---------------- weight prep: WT[l][dst][i][k] bf16 (combined, W^T layout) ----------
__global__ __launch_bounds__(256) void build_wcomb(
    const float* __restrict__ Wl, const float* __restrict__ bl,
    const float* __restrict__ Wr, unsigned short* __restrict__ WT, float* __restrict__ bc)
{
    int idx = blockIdx.x * 256 + threadIdx.x;
    if (idx < 2 * 2 * DD * KTOT) {
        int k  = idx % KTOT;
        int t1 = idx / KTOT;
        int i  = t1 & 127;
        int t2 = t1 >> 7;
        int dt = t2 & 1;      // 0 = dst d, 1 = dst m
        int l  = t2 >> 1;
        int ta = dt ? 1 : 0;  // d: dd(0), m: mm(1)
        int tb = dt ? 2 : 3;  // d: md(3), m: dm(2)
        float v;
        if (k < 128) {
            v = Wl[(((size_t)(l * 4 + ta) * 128 + i) << 7) + k];
        } else if (k < 256) {
            v = Wl[(((size_t)(l * 4 + tb) * 128 + i) << 7) + (k - 128)];
        } else {
            int kk = k - 256;
            v = Wr[(((size_t)(l * 4 + ta) * 128 + i) << 7) + kk]
              + Wr[(((size_t)(l * 4 + tb) * 128 + i) << 7) + kk];
        }
        WT[idx] = f2b(v);
    }
    if (idx < 512) {
        int i  = idx & 127;
        int t2 = idx >> 7;
        int dt = t2 & 1;
        int l  = t2 >> 1;
        int ta = dt ? 1 : 0;
        int tb = dt ? 2 : 3;
        bc[idx] = bl[(l * 4 + ta) * 128 + i] + bl[(l * 4 + tb) * 128 + i];
    }
}

// ---------------- degree counts ----------------
__global__ __launch_bounds__(256) void count_edges_i(const int* __restrict__ ei, int E,
                                                     int* __restrict__ cnt)
{
    int e = blockIdx.x * 256 + threadIdx.x;
    if (e < E) atomicAdd(&cnt[ei[E + e]], 1);
}

__global__ __launch_bounds__(256) void make_inv(const int* __restrict__ cnt,
                                                float* __restrict__ inv, int n)
{
    int i = blockIdx.x * 256 + threadIdx.x;
    if (i < n) inv[i] = 1.0f / (float)max(cnt[i], 1);
}

// ---------------- exclusive scan (3-pass) ----------------
__global__ __launch_bounds__(256) void scan1(const int* __restrict__ in, int n,
                                             int* __restrict__ out, int* __restrict__ bsum)
{
    __shared__ int s[256];
    const int t = threadIdx.x;
    const int base = blockIdx.x * SCAN_TILE + t * 4;
    int c0 = (base + 0) < n ? in[base + 0] : 0;
    int c1 = (base + 1) < n ? in[base + 1] : 0;
    int c2 = (base + 2) < n ? in[base + 2] : 0;
    int c3 = (base + 3) < n ? in[base + 3] : 0;
    int tsum = c0 + c1 + c2 + c3;
    s[t] = tsum;
    __syncthreads();
    for (int d = 1; d < 256; d <<= 1) {
        int v = (t >= d) ? s[t - d] : 0;
        __syncthreads();
        s[t] += v;
        __syncthreads();
    }
    int excl = s[t] - tsum;
    if (base + 0 < n) out[base + 0] = excl;
    if (base + 1 < n) out[base + 1] = excl + c0;
    if (base + 2 < n) out[base + 2] = excl + c0 + c1;
    if (base + 3 < n) out[base + 3] = excl + c0 + c1 + c2;
    if (t == 255) bsum[blockIdx.x] = s[255];
}

__global__ __launch_bounds__(1024) void scan_bsum(int* __restrict__ bsum, int nb)
{
    __shared__ int s[1024];
    const int t = threadIdx.x;
    int v = (t < nb) ? bsum[t] : 0;
    s[t] = v;
    __syncthreads();
    for (int d = 1; d < 1024; d <<= 1) {
        int u = (t >= d) ? s[t - d] : 0;
        __syncthreads();
        s[t] += u;
        __syncthreads();
    }
    if (t < nb) bsum[t] = s[t] - v;   // exclusive
}

__global__ __launch_bounds__(256) void scan_add(int* __restrict__ rp, int* __restrict__ cur,
                                                int n, const int* __restrict__ bsum)
{
    int i = blockIdx.x * 256 + threadIdx.x;
    if (i < n) {
        int v = rp[i] + bsum[i / SCAN_TILE];
        rp[i] = v;
        cur[i] = v;
    }
}

// ---------------- CSR fill ----------------
__global__ __launch_bounds__(256) void fill_csr(const int* __restrict__ ei, int E,
                                                int* __restrict__ cur, int* __restrict__ col)
{
    int e = blockIdx.x * 256 + threadIdx.x;
    if (e < E) {
        int d = ei[E + e];
        int slot = atomicAdd(&cur[d], 1);
        col[slot] = ei[e];
    }
}

// ---------------- gather-aggregate (bf16 in, fp32 accum, bf16 out), 16 lanes/node ------
__global__ __launch_bounds__(256) void aggregate2(
    const unsigned short* __restrict__ xa, const int* __restrict__ rpa,
    const int* __restrict__ cnta, const int* __restrict__ cola, const float* __restrict__ inva,
    const unsigned short* __restrict__ xb, const int* __restrict__ rpb,
    const int* __restrict__ cntb, const int* __restrict__ colb, const float* __restrict__ invb,
    unsigned short* __restrict__ agg0, unsigned short* __restrict__ agg1, int N)
{
    long long g = (long long)blockIdx.x * 256 + threadIdx.x;
    int node = (int)(g >> 4);
    int q    = (int)(g & 15);          // lane handles 8 bf16 = 16 B
    if (node >= N) return;

    float acc[8];
    #pragma unroll
    for (int t = 0; t < 8; ++t) acc[t] = 0.f;
    int s0 = rpa[node], e0 = s0 + cnta[node];
    for (int j = s0; j < e0; ++j) {
        ushort8 v = *(const ushort8*)(xa + (size_t)cola[j] * DD + q * 8);
        #pragma unroll
        for (int t = 0; t < 8; ++t) acc[t] += b2f(v[t]);
    }
    float sc = inva[node];
    ushort8 r;
    #pragma unroll
    for (int t = 0; t < 8; ++t) r[t] = f2b(acc[t] * sc);
    *(ushort8*)(agg0 + (size_t)node * DD + q * 8) = r;

    #pragma unroll
    for (int t = 0; t < 8; ++t) acc[t] = 0.f;
    int s1 = rpb[node], e1 = s1 + cntb[node];
    for (int j = s1; j < e1; ++j) {
        ushort8 v = *(const ushort8*)(xb + (size_t)colb[j] * DD + q * 8);
        #pragma unroll
        for (int t = 0; t < 8; ++t) acc[t] += b2f(v[t]);
    }
    sc = invb[node];
    #pragma unroll
    for (int t = 0; t < 8; ++t) r[t] = f2b(acc[t] * sc);
    *(ushort8*)(agg1 + (size_t)node * DD + q * 8) = r;
}

// ---------------- MFMA GEMM: out = [agg_a | agg_b | x](bf16) @ WT^T + bc (+relu) --------
__global__ __launch_bounds__(256) void gemm_mfma(
    const unsigned short* __restrict__ agg_a, const unsigned short* __restrict__ agg_b,
    const unsigned short* __restrict__ xs, const unsigned short* __restrict__ WT,
    const float* __restrict__ bias, void* __restrict__ outp,
    int relu, int write_f32, int N)
{
    __shared__ unsigned short As[BM * LDK];      // 50176 B
    const int tid  = threadIdx.x;
    const int row0 = blockIdx.x * BM;

    // stage A tile: 64 rows x 48 chunks(16B) = 3072 chunks, 12/thread, coalesced
    #pragma unroll
    for (int it = 0; it < 12; ++it) {
        int i   = tid + it * 256;
        int row = i / 48;
        int c   = i - row * 48;
        int seg = c >> 4;
        int kk  = c & 15;
        int rg  = row0 + row;
        if (rg >= N) rg = N - 1;
        const unsigned short* src = (seg == 0) ? agg_a : (seg == 1) ? agg_b : xs;
        uint4 v = *(const uint4*)(src + (size_t)rg * DD + kk * 8);
        *(uint4*)(&As[row * LDK + seg * 128 + kk * 8]) = v;
    }
    __syncthreads();

    const int wave = tid >> 6;
    const int lane = tid & 63;
    const int wr = (wave >> 1) * 32;         // 0 / 32
    const int wc = (wave & 1) * 64;          // 0 / 64
    const int fr = lane & 15;
    const int fk = (lane >> 4) * 8;

    floatx4 acc[2][4] = {};
    const unsigned short* wbase = WT + (size_t)(wc + fr) * KTOT + fk;

    short8 a0c, a1c, a0n, a1n, bC[4], bN[4];
    a0c = *(const short8*)(&As[(wr      + fr) * LDK + fk]);
    a1c = *(const short8*)(&As[(wr + 16 + fr) * LDK + fk]);
    #pragma unroll
    for (int c = 0; c < 4; ++c) bC[c] = *(const short8*)(wbase + (size_t)c * 16 * KTOT);

    #pragma unroll
    for (int ks = 0; ks < 12; ++ks) {
        if (ks < 11) {
            int k1 = (ks + 1) * 32;
            a0n = *(const short8*)(&As[(wr      + fr) * LDK + k1 + fk]);
            a1n = *(const short8*)(&As[(wr + 16 + fr) * LDK + k1 + fk]);
            #pragma unroll
            for (int c = 0; c < 4; ++c) bN[c] = *(const short8*)(wbase + (size_t)c * 16 * KTOT + k1);
        }
        #pragma unroll
        for (int c = 0; c < 4; ++c) {
            acc[0][c] = __builtin_amdgcn_mfma_f32_16x16x32_bf16(a0c, bC[c], acc[0][c], 0, 0, 0);
            acc[1][c] = __builtin_amdgcn_mfma_f32_16x16x32_bf16(a1c, bC[c], acc[1][c], 0, 0, 0);
        }
        a0c = a0n; a1c = a1n;
        #pragma unroll
        for (int c = 0; c < 4; ++c) bC[c] = bN[c];
    }

    // epilogue: col = wc + c*16 + (lane&15), row = wr + m*16 + (lane>>4)*4 + i   [m89 layout]
    float* outf = (float*)outp;
    unsigned short* outb = (unsigned short*)outp;
    const int rb = (lane >> 4) * 4;
    #pragma unroll
    for (int c = 0; c < 4; ++c) {
        int col = wc + c * 16 + fr;
        float bb = bias[col];
        #pragma unroll
        for (int m = 0; m < 2; ++m) {
            #pragma unroll
            for (int i = 0; i < 4; ++i) {
                int row = row0 + wr + m * 16 + rb + i;
                if (row >= N) continue;
                float v = acc[m][c][i] + bb;
                if (relu) v = fmaxf(v, 0.f);
                if (write_f32) outf[(size_t)row * DD + col] = v;
                else           outb[(size_t)row * DD + col] = f2b(v);
            }
        }
    }
}

extern "C" void kernel_launch(void* const* d_in, const int* in_sizes, int n_in,
                              void* d_out, int out_size, void* d_ws, size_t ws_size,
                              hipStream_t stream)
{
    const float* x_d = (const float*)d_in[0];
    const float* x_m = (const float*)d_in[1];
    const float* Wl  = (const float*)d_in[6];
    const float* bl  = (const float*)d_in[7];
    const float* Wr  = (const float*)d_in[8];
    float* out = (float*)d_out;

    const int N    = in_sizes[0] / DD;
    const int E_dd = in_sizes[2] / 2;
    const int E_mm = in_sizes[3] / 2;
    const int E_dm = in_sizes[4] / 2;
    const int E_md = in_sizes[5] / 2;

    char* ws = (char*)d_ws;
    size_t off = 0;
    auto alloc = [&](size_t bytes) {
        void* p = ws + off;
        off += (bytes + 255) & ~(size_t)255;
        return p;
    };
    unsigned short* xb_d  = (unsigned short*)alloc((size_t)N * DD * 2);
    unsigned short* xb_m  = (unsigned short*)alloc((size_t)N * DD * 2);
    unsigned short* hb_d  = (unsigned short*)alloc((size_t)N * DD * 2);
    unsigned short* hb_m  = (unsigned short*)alloc((size_t)N * DD * 2);
    unsigned short* agg0  = (unsigned short*)alloc((size_t)N * DD * 2);
    unsigned short* agg1  = (unsigned short*)alloc((size_t)N * DD * 2);
    int*   cnt_all = (int*)  alloc((size_t)4 * N * 4);   // dd|md|mm|dm
    float* inv_all = (float*)alloc((size_t)4 * N * 4);
    int*   rp_all  = (int*)  alloc((size_t)4 * N * 4);
    int*   cur_all = (int*)  alloc((size_t)4 * N * 4);
    int*   bsum    = (int*)  alloc((size_t)4 * 1024 * 4);
    unsigned short* WT = (unsigned short*)alloc((size_t)2 * 2 * DD * KTOT * 2);
    float* bc      = (float*)alloc((size_t)512 * 4);
    int*   ce_dd   = (int*)alloc((size_t)2 * E_dd * 4);
    int*   ce_mm   = (int*)alloc((size_t)2 * E_mm * 4);
    int*   ce_dm   = (int*)alloc((size_t)2 * E_dm * 4);
    int*   ce_md   = (int*)alloc((size_t)2 * E_md * 4);
    int*   col_dd  = (int*)alloc((size_t)E_dd * 4);
    int*   col_md  = (int*)alloc((size_t)E_md * 4);
    int*   col_mm  = (int*)alloc((size_t)E_mm * 4);
    int*   col_dm  = (int*)alloc((size_t)E_dm * 4);
    int*   flag    = (int*)alloc(256);

    int*   cnt_dd = cnt_all,  *cnt_md = cnt_all + N, *cnt_mm = cnt_all + 2*N, *cnt_dm = cnt_all + 3*N;
    float* inv_dd = inv_all,  *inv_md = inv_all + N, *inv_mm = inv_all + 2*N, *inv_dm = inv_all + 3*N;
    int*   rp_dd  = rp_all,   *rp_md  = rp_all + N,  *rp_mm  = rp_all + 2*N,  *rp_dm  = rp_all + 3*N;
    int*   cur_dd = cur_all,  *cur_md = cur_all + N, *cur_mm = cur_all + 2*N, *cur_dm = cur_all + 3*N;

    // ---- edge dtype normalize ----
    hipMemsetAsync(flag, 0, 256, stream);
    detect_i32<<<4, 256, 0, stream>>>((const int*)d_in[2], 1024, flag);
    convert_edges<<<(2 * E_dd + 255) / 256, 256, 0, stream>>>(d_in[2], 2 * E_dd, flag, ce_dd);
    convert_edges<<<(2 * E_mm + 255) / 256, 256, 0, stream>>>(d_in[3], 2 * E_mm, flag, ce_mm);
    convert_edges<<<(2 * E_dm + 255) / 256, 256, 0, stream>>>(d_in[4], 2 * E_dm, flag, ce_dm);
    convert_edges<<<(2 * E_md + 255) / 256, 256, 0, stream>>>(d_in[5], 2 * E_md, flag, ce_md);

    // ---- x -> bf16 ----
    const int n8 = N * DD / 8;
    cvt_bf16<<<(n8 + 255) / 256, 256, 0, stream>>>(x_d, xb_d, n8);
    cvt_bf16<<<(n8 + 255) / 256, 256, 0, stream>>>(x_m, xb_m, n8);

    // ---- degrees + inverse means ----
    hipMemsetAsync(cnt_all, 0, (size_t)4 * N * 4, stream);
    count_edges_i<<<(E_dd + 255) / 256, 256, 0, stream>>>(ce_dd, E_dd, cnt_dd);
    count_edges_i<<<(E_md + 255) / 256, 256, 0, stream>>>(ce_md, E_md, cnt_md);
    count_edges_i<<<(E_mm + 255) / 256, 256, 0, stream>>>(ce_mm, E_mm, cnt_mm);
    count_edges_i<<<(E_dm + 255) / 256, 256, 0, stream>>>(ce_dm, E_dm, cnt_dm);
    make_inv<<<(4 * N + 255) / 256, 256, 0, stream>>>(cnt_all, inv_all, 4 * N);

    // ---- CSR build (once; layer-invariant) ----
    const int nsb = (N + SCAN_TILE - 1) / SCAN_TILE;
    for (int t = 0; t < 4; ++t) {
        int* cnt = cnt_all + t * N;
        int* rp  = rp_all  + t * N;
        int* cur = cur_all + t * N;
        int* bs  = bsum + t * 1024;
        scan1<<<nsb, 256, 0, stream>>>(cnt, N, rp, bs);
        scan_bsum<<<1, 1024, 0, stream>>>(bs, nsb);
        scan_add<<<(N + 255) / 256, 256, 0, stream>>>(rp, cur, N, bs);
    }
    fill_csr<<<(E_dd + 255) / 256, 256, 0, stream>>>(ce_dd, E_dd, cur_dd, col_dd);
    fill_csr<<<(E_md + 255) / 256, 256, 0, stream>>>(ce_md, E_md, cur_md, col_md);
    fill_csr<<<(E_mm + 255) / 256, 256, 0, stream>>>(ce_mm, E_mm, cur_mm, col_mm);
    fill_csr<<<(E_dm + 255) / 256, 256, 0, stream>>>(ce_dm, E_dm, cur_dm, col_dm);

    build_wcomb<<<(2 * 2 * DD * KTOT + 255) / 256, 256, 0, stream>>>(Wl, bl, Wr, WT, bc);

    const int agg_grid  = (int)(((size_t)N * 16 + 255) / 256);
    const int gemm_grid = (N + BM - 1) / BM;
    const unsigned short* xd_cur = xb_d;
    const unsigned short* xm_cur = xb_m;
    for (int l = 0; l < 2; ++l) {
        int relu = (l == 0);
        int wf32 = (l == 1);
        void* od = (l == 1) ? (void*)out : (void*)hb_d;
        void* om = (l == 1) ? (void*)(out + (size_t)N * DD) : (void*)hb_m;

        // dst type d: agg_dd (x_d via e_dd) + agg_md (x_m via e_md)
        aggregate2<<<agg_grid, 256, 0, stream>>>(
            xd_cur, rp_dd, cnt_dd, col_dd, inv_dd,
            xm_cur, rp_md, cnt_md, col_md, inv_md, agg0, agg1, N);
        gemm_mfma<<<gemm_grid, 256, 0, stream>>>(
            agg0, agg1, xd_cur, WT + (size_t)(l * 2 + 0) * DD * KTOT,
            bc + (l * 2 + 0) * DD, od, relu, wf32, N);

        // dst type m: agg_mm (x_m via e_mm) + agg_dm (x_d via e_dm)
        aggregate2<<<agg_grid, 256, 0, stream>>>(
            xm_cur, rp_mm, cnt_mm, col_mm, inv_mm,
            xd_cur, rp_dm, cnt_dm, col_dm, inv_dm, agg0, agg1, N);
        gemm_mfma<<<gemm_grid, 256, 0, stream>>>(
            agg0, agg1, xm_cur, WT + (size_t)(l * 2 + 1) * DD * KTOT,
            bc + (l * 2 + 1) * DD, om, relu, wf32, N);

        xd_cur = hb_d;
        xm_cur = hb_m;
    }
}